// Round 1
// baseline (150.732 us; speedup 1.0000x reference)
//
#include <hip/hip_runtime.h>

typedef unsigned short u16;
typedef unsigned int u32;
typedef __bf16 bfx8 __attribute__((ext_vector_type(8)));
typedef float f32x4 __attribute__((ext_vector_type(4)));

#define HIDDEN 1024
#define HEADS 16
#define HDIM 64
#define SEQ 2048
#define LOG2E 1.44269504f

__device__ __forceinline__ u16 f2bf(float f) {
  u32 u = __builtin_bit_cast(u32, f);
  u += 0x7fffu + ((u >> 16) & 1u);
  return (u16)(u >> 16);
}

#define GLOAD_LDS16(g, l)                                                       \
  __builtin_amdgcn_global_load_lds(                                             \
      (const __attribute__((address_space(1))) void*)(g),                       \
      (__attribute__((address_space(3))) void*)(l), 16, 0, 0)

// ---------------- cast hidden fp32 -> bf16 ----------------
__global__ __launch_bounds__(256) void cast_bf16_kernel(
    const float* __restrict__ src, u16* __restrict__ dst, int n4) {
  int idx = blockIdx.x * blockDim.x + threadIdx.x;
  int stride = gridDim.x * blockDim.x;
  for (int i = idx; i < n4; i += stride) {
    float4 v = ((const float4*)src)[i];
    ushort4 o;
    o.x = f2bf(v.x); o.y = f2bf(v.y); o.z = f2bf(v.z); o.w = f2bf(v.w);
    ((ushort4*)dst)[i] = o;
  }
}

// ------------- transpose-cast W[k][n] fp32 -> Wt[n][k] bf16 -------------
__global__ __launch_bounds__(256) void transpose_cast_kernel(
    const float* __restrict__ W, u16* __restrict__ Wt) {
  __shared__ u16 tile[64][65];
  const int kt = blockIdx.y * 64, nt = blockIdx.x * 64;
  const int t = threadIdx.x;
#pragma unroll
  for (int it = 0; it < 16; ++it) {
    int kl = it * 4 + (t >> 6), nl = t & 63;
    tile[kl][nl] = f2bf(W[(size_t)(kt + kl) * HIDDEN + nt + nl]);
  }
  __syncthreads();
#pragma unroll
  for (int it = 0; it < 16; ++it) {
    int nl = it * 4 + (t >> 6), kl = t & 63;
    Wt[(size_t)(nt + nl) * HIDDEN + kt + kl] = tile[kl][nl];
  }
}

// ---------------- shared 128x128 bf16 MFMA GEMM core (m97 structure) ----------------
// A: [M][K] bf16 row-major. Bt: [N][K] bf16 row-major (i.e. B transposed).
__device__ __forceinline__ void gemm_core(const u16* __restrict__ A,
                                          const u16* __restrict__ Bt, int K,
                                          int m0, int n0, u16* As, u16* Bs,
                                          f32x4 acc[4][4]) {
  const int lane = threadIdx.x & 63;
  const int wave = threadIdx.x >> 6;
  const int wm = wave >> 1, wn = wave & 1;
  const int lrow = lane >> 2;        // 0..15 row within 16-row staging chunk
  const int lcol = (lane & 3) * 8;   // k element offset within 32
  const f32x4 zero = {0.f, 0.f, 0.f, 0.f};
#pragma unroll
  for (int i = 0; i < 4; ++i)
#pragma unroll
    for (int j = 0; j < 4; ++j) acc[i][j] = zero;

  for (int kt = 0; kt < K; kt += 32) {
    __syncthreads();  // previous iteration's LDS reads done
#pragma unroll
    for (int c2 = 0; c2 < 2; ++c2) {
      const int c = wave * 2 + c2;       // 1KB chunk id (0..7)
      const int r = c * 16 + lrow;       // tile row 0..127
      GLOAD_LDS16(A + (size_t)(m0 + r) * K + kt + lcol, As + c * 512);
      GLOAD_LDS16(Bt + (size_t)(n0 + r) * K + kt + lcol, Bs + c * 512);
    }
    __syncthreads();  // drains vmcnt -> staged data visible
    bfx8 af[4], bf[4];
#pragma unroll
    for (int f = 0; f < 4; ++f) {
      af[f] = *(const bfx8*)(As + (wm * 64 + f * 16 + (lane & 15)) * 32 + (lane >> 4) * 8);
      bf[f] = *(const bfx8*)(Bs + (wn * 64 + f * 16 + (lane & 15)) * 32 + (lane >> 4) * 8);
    }
#pragma unroll
    for (int fm = 0; fm < 4; ++fm)
#pragma unroll
      for (int fn = 0; fn < 4; ++fn)
        acc[fm][fn] = __builtin_amdgcn_mfma_f32_16x16x32_bf16(af[fm], bf[fn], acc[fm][fn], 0, 0, 0);
  }
}

// ---------------- QKV projection + scatter epilogue ----------------
__global__ __launch_bounds__(256) void gemm_qkv_kernel(
    const u16* __restrict__ A, const u16* __restrict__ Bt,
    const float* __restrict__ bq, const float* __restrict__ bk,
    const float* __restrict__ bv, u16* __restrict__ qo, u16* __restrict__ ko,
    u16* __restrict__ vto) {
  __shared__ alignas(16) u16 As[128 * 32];
  __shared__ alignas(16) u16 Bs[128 * 32];
  f32x4 acc[4][4];
  const int m0 = blockIdx.y * 128, n0 = blockIdx.x * 128;
  gemm_core(A, Bt, HIDDEN, m0, n0, As, Bs, acc);
  const int lane = threadIdx.x & 63;
  const int wave = threadIdx.x >> 6;
  const int wm = wave >> 1, wn = wave & 1;
#pragma unroll
  for (int fn = 0; fn < 4; ++fn) {
    const int n = n0 + wn * 64 + fn * 16 + (lane & 15);
    const int which = n >> 10;   // 0=q 1=k 2=v
    const int nn = n & 1023;
    const float bias = (which == 0 ? bq : which == 1 ? bk : bv)[nn];
    const int hh = nn >> 6, d = nn & 63;
#pragma unroll
    for (int fm = 0; fm < 4; ++fm) {
#pragma unroll
      for (int r = 0; r < 4; ++r) {
        const int m = m0 + wm * 64 + fm * 16 + (lane >> 4) * 4 + r;
        const int bb = m >> 11, s = m & (SEQ - 1);
        const int bh = bb * HEADS + hh;
        const u16 val = f2bf(acc[fm][fn][r] + bias);
        if (which == 0)      qo[((size_t)bh * SEQ + s) * HDIM + d] = val;
        else if (which == 1) ko[((size_t)bh * SEQ + s) * HDIM + d] = val;
        else                 vto[((size_t)bh * HDIM + d) * SEQ + s] = val;  // V^T
      }
    }
  }
}

// ---------------- output projection ----------------
__global__ __launch_bounds__(256) void gemm_out_kernel(
    const u16* __restrict__ A, const u16* __restrict__ Bt,
    const float* __restrict__ bo, float* __restrict__ out) {
  __shared__ alignas(16) u16 As[128 * 32];
  __shared__ alignas(16) u16 Bs[128 * 32];
  f32x4 acc[4][4];
  const int m0 = blockIdx.y * 128, n0 = blockIdx.x * 128;
  gemm_core(A, Bt, HIDDEN, m0, n0, As, Bs, acc);
  const int lane = threadIdx.x & 63;
  const int wave = threadIdx.x >> 6;
  const int wm = wave >> 1, wn = wave & 1;
#pragma unroll
  for (int fm = 0; fm < 4; ++fm)
#pragma unroll
    for (int fn = 0; fn < 4; ++fn) {
      const int n = n0 + wn * 64 + fn * 16 + (lane & 15);
      const float bias = bo[n];
#pragma unroll
      for (int r = 0; r < 4; ++r) {
        const int m = m0 + wm * 64 + fm * 16 + (lane >> 4) * 4 + r;
        out[(size_t)m * HIDDEN + n] = acc[fm][fn][r] + bias;
      }
    }
}

// ---------------- sliding-window + global-token attention ----------------
// 1 wave per (b, h, 16-query tile). K chunks of 32 keys, online softmax.
__global__ __launch_bounds__(64) void attn_kernel(
    const u16* __restrict__ q, const u16* __restrict__ k,
    const u16* __restrict__ vt, u16* __restrict__ ctx,
    const int* __restrict__ wsz) {
  const int lane = threadIdx.x;
  const int i0 = blockIdx.x * 16;
  const int h = blockIdx.y, b = blockIdx.z;
  const int bh = b * HEADS + h;
  const int half = wsz[0] >> 1;

  __shared__ alignas(16) u16 P[2][16][40];  // stride 40 breaks bank conflicts

  const u16* qb = q + (size_t)bh * SEQ * HDIM;
  const u16* kb = k + (size_t)bh * SEQ * HDIM;
  const u16* vb = vt + (size_t)bh * HDIM * SEQ;

  bfx8 qa[2];
  {
    const int qrow = i0 + (lane & 15);
#pragma unroll
    for (int ks = 0; ks < 2; ++ks)
      qa[ks] = *(const bfx8*)(qb + (size_t)qrow * HDIM + ks * 32 + (lane >> 4) * 8);
  }

  float mr[4], lr[4];
  f32x4 ctxa[4];
  const f32x4 zero = {0.f, 0.f, 0.f, 0.f};
#pragma unroll
  for (int r = 0; r < 4; ++r) { mr[r] = -1e4f; lr[r] = 0.f; }
#pragma unroll
  for (int dt = 0; dt < 4; ++dt) ctxa[dt] = zero;

  int wlo = i0 - half; if (wlo < 0) wlo = 0; wlo &= ~31;
  int whi = i0 + 15 + half; if (whi > SEQ - 1) whi = SEQ - 1;

  int parity = 0;
  for (int ci = (wlo > 0 ? -1 : 0); ; ++ci, parity ^= 1) {
    const int j0 = (ci < 0) ? 0 : wlo + ci * 32;   // ci==-1: global j=0 chunk
    if (j0 > whi) break;

    // ---- scores: Q (A-frag) x K^T (B-frag) ----
    f32x4 sc[2];
#pragma unroll
    for (int nt = 0; nt < 2; ++nt) {
      f32x4 c = zero;
      const int j = j0 + nt * 16 + (lane & 15);
      const int jc = j < SEQ ? j : SEQ - 1;
#pragma unroll
      for (int ks = 0; ks < 2; ++ks) {
        const bfx8 kf = *(const bfx8*)(kb + (size_t)jc * HDIM + ks * 32 + (lane >> 4) * 8);
        c = __builtin_amdgcn_mfma_f32_16x16x32_bf16(qa[ks], kf, c, 0, 0, 0);
      }
      sc[nt] = c;
    }

    // ---- mask + online softmax (rows owned per-reg, reduce over 16 lanes) ----
#pragma unroll
    for (int r = 0; r < 4; ++r) {
      const int i = i0 + (lane >> 4) * 4 + r;
#pragma unroll
      for (int nt = 0; nt < 2; ++nt) {
        const int j = j0 + nt * 16 + (lane & 15);
        int dd = i - j; if (dd < 0) dd = -dd;
        const bool ok = (j < SEQ) && (dd <= half || j == 0);
        sc[nt][r] = ok ? sc[nt][r] * 0.125f : -1e4f;
      }
      float cm = fmaxf(sc[0][r], sc[1][r]);
      cm = fmaxf(cm, __shfl_xor(cm, 1));
      cm = fmaxf(cm, __shfl_xor(cm, 2));
      cm = fmaxf(cm, __shfl_xor(cm, 4));
      cm = fmaxf(cm, __shfl_xor(cm, 8));
      const float mnew = fmaxf(mr[r], cm);
      const float alpha = exp2f((mr[r] - mnew) * LOG2E);
      mr[r] = mnew;
      const float p0 = exp2f((sc[0][r] - mnew) * LOG2E);
      const float p1 = exp2f((sc[1][r] - mnew) * LOG2E);
      float ps = p0 + p1;
      ps += __shfl_xor(ps, 1);
      ps += __shfl_xor(ps, 2);
      ps += __shfl_xor(ps, 4);
      ps += __shfl_xor(ps, 8);
      lr[r] = lr[r] * alpha + ps;
#pragma unroll
      for (int dt = 0; dt < 4; ++dt) ctxa[dt][r] *= alpha;
      const int row = (lane >> 4) * 4 + r;
      P[parity][row][lane & 15] = f2bf(p0);
      P[parity][row][16 + (lane & 15)] = f2bf(p1);
    }
    __syncthreads();

    // ---- PV: P (A-frag from LDS) x V^T rows (contiguous B-frag) ----
    const bfx8 pa = *(const bfx8*)(&P[parity][lane & 15][(lane >> 4) * 8]);
    int sidx = j0 + (lane >> 4) * 8;
    if (sidx > SEQ - 8) sidx = SEQ - 8;  // masked keys have p=0
#pragma unroll
    for (int dt = 0; dt < 4; ++dt) {
      const bfx8 vf = *(const bfx8*)(vb + (size_t)(dt * 16 + (lane & 15)) * SEQ + sidx);
      ctxa[dt] = __builtin_amdgcn_mfma_f32_16x16x32_bf16(pa, vf, ctxa[dt], 0, 0, 0);
    }
  }

#pragma unroll
  for (int r = 0; r < 4; ++r) {
    const float inv = 1.0f / lr[r];
    const int i = i0 + (lane >> 4) * 4 + r;
    const size_t base = ((size_t)b * SEQ + i) * HIDDEN + h * HDIM;
#pragma unroll
    for (int dt = 0; dt < 4; ++dt)
      ctx[base + dt * 16 + (lane & 15)] = f2bf(ctxa[dt][r] * inv);
  }
}

extern "C" void kernel_launch(void* const* d_in, const int* in_sizes, int n_in,
                              void* d_out, int out_size, void* d_ws, size_t ws_size,
                              hipStream_t stream) {
  const float* hs = (const float*)d_in[0];
  const float* Wq = (const float*)d_in[1];
  const float* bq = (const float*)d_in[2];
  const float* Wk = (const float*)d_in[3];
  const float* bk = (const float*)d_in[4];
  const float* Wv = (const float*)d_in[5];
  const float* bv = (const float*)d_in[6];
  const float* Wo = (const float*)d_in[7];
  const float* bo = (const float*)d_in[8];
  const int* wsz  = (const int*)d_in[9];
  float* out = (float*)d_out;

  const int BS = in_sizes[0] / HIDDEN;  // B*S = 4096
  const int B = BS / SEQ;               // 2

  u16* ws    = (u16*)d_ws;
  u16* hsb   = ws;                                  // [BS][1024] bf16 (reused as ctx)
  u16* wqkvt = hsb + (size_t)BS * HIDDEN;           // [3072][1024] bf16 (Wqkv^T)
  u16* wot   = wqkvt + (size_t)3 * HIDDEN * HIDDEN; // [1024][1024] bf16 (Wo^T)
  u16* qb    = wot + (size_t)HIDDEN * HIDDEN;       // [B*H][S][64]
  u16* kb    = qb + (size_t)BS * HIDDEN;
  u16* vtb   = kb + (size_t)BS * HIDDEN;            // [B*H][64][S]  (V^T)
  u16* ctxb  = hsb;                                 // alias: hsb dead after QKV GEMM

  cast_bf16_kernel<<<dim3(1024), dim3(256), 0, stream>>>(hs, hsb, BS * HIDDEN / 4);
  transpose_cast_kernel<<<dim3(16, 16), dim3(256), 0, stream>>>(Wq, wqkvt);
  transpose_cast_kernel<<<dim3(16, 16), dim3(256), 0, stream>>>(Wk, wqkvt + (size_t)HIDDEN * HIDDEN);
  transpose_cast_kernel<<<dim3(16, 16), dim3(256), 0, stream>>>(Wv, wqkvt + (size_t)2 * HIDDEN * HIDDEN);
  transpose_cast_kernel<<<dim3(16, 16), dim3(256), 0, stream>>>(Wo, wot);

  gemm_qkv_kernel<<<dim3(3 * HIDDEN / 128, BS / 128), dim3(256), 0, stream>>>(
      hsb, wqkvt, bq, bk, bv, qb, kb, vtb);

  attn_kernel<<<dim3(SEQ / 16, HEADS, B), dim3(64), 0, stream>>>(qb, kb, vtb, ctxb, wsz);

  gemm_out_kernel<<<dim3(HIDDEN / 128, BS / 128), dim3(256), 0, stream>>>(ctxb, wot, bo, out);
}

// Round 2
// 122.155 us; speedup vs baseline: 1.2339x; 1.2339x over previous
//
#include <hip/hip_runtime.h>

typedef unsigned short u16;
typedef unsigned int u32;
typedef __bf16 bfx8 __attribute__((ext_vector_type(8)));
typedef float f32x4 __attribute__((ext_vector_type(4)));

#define HIDDEN 1024
#define HEADS 16
#define HDIM 64
#define SEQ 2048
#define LOG2E 1.44269504f

__device__ __forceinline__ u16 f2bf(float f) {
  u32 u = __builtin_bit_cast(u32, f);
  u += 0x7fffu + ((u >> 16) & 1u);
  return (u16)(u >> 16);
}
__device__ __forceinline__ float bf2f(u16 v) {
  u32 u = ((u32)v) << 16;
  return __builtin_bit_cast(float, u);
}

#define GLOAD_LDS16(g, l)                                                       \
  __builtin_amdgcn_global_load_lds(                                             \
      (const __attribute__((address_space(1))) void*)(g),                       \
      (__attribute__((address_space(3))) void*)(l), 16, 0, 0)

// ---------------- cast hidden fp32 -> bf16 ----------------
__global__ __launch_bounds__(256) void cast_bf16_kernel(
    const float* __restrict__ src, u16* __restrict__ dst, int n4) {
  int idx = blockIdx.x * blockDim.x + threadIdx.x;
  int stride = gridDim.x * blockDim.x;
  for (int i = idx; i < n4; i += stride) {
    float4 v = ((const float4*)src)[i];
    ushort4 o;
    o.x = f2bf(v.x); o.y = f2bf(v.y); o.z = f2bf(v.z); o.w = f2bf(v.w);
    ((ushort4*)dst)[i] = o;
  }
}

// ------------- transpose-cast 4 weights W[k][n] fp32 -> Wt[n][k] bf16 -------------
__global__ __launch_bounds__(256) void transpose_cast4_kernel(
    const float* __restrict__ W0, const float* __restrict__ W1,
    const float* __restrict__ W2, const float* __restrict__ W3,
    u16* __restrict__ dstbase) {
  __shared__ u16 tile[64][65];
  const float* W = blockIdx.z == 0 ? W0 : blockIdx.z == 1 ? W1
                  : blockIdx.z == 2 ? W2 : W3;
  u16* Wt = dstbase + (size_t)blockIdx.z * HIDDEN * HIDDEN;
  const int kt = blockIdx.y * 64, nt = blockIdx.x * 64;
  const int t = threadIdx.x;
#pragma unroll
  for (int it = 0; it < 16; ++it) {
    int kl = it * 4 + (t >> 6), nl = t & 63;
    tile[kl][nl] = f2bf(W[(size_t)(kt + kl) * HIDDEN + nt + nl]);
  }
  __syncthreads();
#pragma unroll
  for (int it = 0; it < 16; ++it) {
    int nl = it * 4 + (t >> 6), kl = t & 63;
    Wt[(size_t)(nt + nl) * HIDDEN + kt + kl] = tile[kl][nl];
  }
}

// ---------------- shared 128x128 bf16 MFMA GEMM core (m97 structure) ----------------
__device__ __forceinline__ void gemm_core(const u16* __restrict__ A,
                                          const u16* __restrict__ Bt, int K,
                                          int m0, int n0, u16* As, u16* Bs,
                                          f32x4 acc[4][4]) {
  const int lane = threadIdx.x & 63;
  const int wave = threadIdx.x >> 6;
  const int wm = wave >> 1, wn = wave & 1;
  const int lrow = lane >> 2;
  const int lcol = (lane & 3) * 8;
  const f32x4 zero = {0.f, 0.f, 0.f, 0.f};
#pragma unroll
  for (int i = 0; i < 4; ++i)
#pragma unroll
    for (int j = 0; j < 4; ++j) acc[i][j] = zero;

  for (int kt = 0; kt < K; kt += 32) {
    __syncthreads();
#pragma unroll
    for (int c2 = 0; c2 < 2; ++c2) {
      const int c = wave * 2 + c2;
      const int r = c * 16 + lrow;
      GLOAD_LDS16(A + (size_t)(m0 + r) * K + kt + lcol, As + c * 512);
      GLOAD_LDS16(Bt + (size_t)(n0 + r) * K + kt + lcol, Bs + c * 512);
    }
    __syncthreads();
    bfx8 af[4], bf[4];
#pragma unroll
    for (int f = 0; f < 4; ++f) {
      af[f] = *(const bfx8*)(As + (wm * 64 + f * 16 + (lane & 15)) * 32 + (lane >> 4) * 8);
      bf[f] = *(const bfx8*)(Bs + (wn * 64 + f * 16 + (lane & 15)) * 32 + (lane >> 4) * 8);
    }
#pragma unroll
    for (int fm = 0; fm < 4; ++fm)
#pragma unroll
      for (int fn = 0; fn < 4; ++fn)
        acc[fm][fn] = __builtin_amdgcn_mfma_f32_16x16x32_bf16(af[fm], bf[fn], acc[fm][fn], 0, 0, 0);
  }
}

// ---------------- QKV projection + scatter epilogue ----------------
__global__ __launch_bounds__(256) void gemm_qkv_kernel(
    const u16* __restrict__ A, const u16* __restrict__ Bt,
    const float* __restrict__ bq, const float* __restrict__ bk,
    const float* __restrict__ bv, u16* __restrict__ qo, u16* __restrict__ ko,
    u16* __restrict__ vto) {
  __shared__ alignas(16) u16 As[128 * 32];
  __shared__ alignas(16) u16 Bs[128 * 32];
  f32x4 acc[4][4];
  const int m0 = blockIdx.y * 128, n0 = blockIdx.x * 128;
  gemm_core(A, Bt, HIDDEN, m0, n0, As, Bs, acc);
  const int lane = threadIdx.x & 63;
  const int wave = threadIdx.x >> 6;
  const int wm = wave >> 1, wn = wave & 1;
#pragma unroll
  for (int fn = 0; fn < 4; ++fn) {
    const int n = n0 + wn * 64 + fn * 16 + (lane & 15);
    const int which = n >> 10;
    const int nn = n & 1023;
    const float bias = (which == 0 ? bq : which == 1 ? bk : bv)[nn];
    const int hh = nn >> 6, d = nn & 63;
#pragma unroll
    for (int fm = 0; fm < 4; ++fm) {
#pragma unroll
      for (int r = 0; r < 4; ++r) {
        const int m = m0 + wm * 64 + fm * 16 + (lane >> 4) * 4 + r;
        const int bb = m >> 11, s = m & (SEQ - 1);
        const int bh = bb * HEADS + hh;
        const u16 val = f2bf(acc[fm][fn][r] + bias);
        if (which == 0)      qo[((size_t)bh * SEQ + s) * HDIM + d] = val;
        else if (which == 1) ko[((size_t)bh * SEQ + s) * HDIM + d] = val;
        else                 vto[((size_t)bh * HDIM + d) * SEQ + s] = val;  // V^T
      }
    }
  }
}

// ---------------- output projection ----------------
__global__ __launch_bounds__(256) void gemm_out_kernel(
    const u16* __restrict__ A, const u16* __restrict__ Bt,
    const float* __restrict__ bo, float* __restrict__ out) {
  __shared__ alignas(16) u16 As[128 * 32];
  __shared__ alignas(16) u16 Bs[128 * 32];
  f32x4 acc[4][4];
  const int m0 = blockIdx.y * 128, n0 = blockIdx.x * 128;
  gemm_core(A, Bt, HIDDEN, m0, n0, As, Bs, acc);
  const int lane = threadIdx.x & 63;
  const int wave = threadIdx.x >> 6;
  const int wm = wave >> 1, wn = wave & 1;
#pragma unroll
  for (int fm = 0; fm < 4; ++fm)
#pragma unroll
    for (int fn = 0; fn < 4; ++fn) {
      const int n = n0 + wn * 64 + fn * 16 + (lane & 15);
      const float bias = bo[n];
#pragma unroll
      for (int r = 0; r < 4; ++r) {
        const int m = m0 + wm * 64 + fm * 16 + (lane >> 4) * 4 + r;
        out[(size_t)m * HIDDEN + n] = acc[fm][fn][r] + bias;
      }
    }
}

// ---------------- sliding-window + global-token attention (v2) ----------------
// 1 wave per (b,h,16-query tile). Fixed softmax shift (m=0): no online max, no
// rescale, no per-chunk cross-lane ops. K-frags double-buffered (1 chunk ahead).
// No __syncthreads in the loop (would drain vmcnt and kill the prefetch).
#define ATTN_STEP(KFC, KFN, PAR)                                                 \
  {                                                                             \
    const int j0 = wlo + (c << 5);                                              \
    int sidx = j0 + lg * 8;                                                     \
    if (sidx > SEQ - 8) sidx = SEQ - 8;                                         \
    const bfx8 vf0 = *(const bfx8*)(vb + (size_t)(li) * SEQ + sidx);            \
    const bfx8 vf1 = *(const bfx8*)(vb + (size_t)(16 + li) * SEQ + sidx);       \
    const bfx8 vf2 = *(const bfx8*)(vb + (size_t)(32 + li) * SEQ + sidx);       \
    const bfx8 vf3 = *(const bfx8*)(vb + (size_t)(48 + li) * SEQ + sidx);       \
    if (c + 1 < nc) {                                                           \
      const int j1 = j0 + 32;                                                   \
      int ja = j1 + li;      if (ja > SEQ - 1) ja = SEQ - 1;                    \
      int jb = j1 + 16 + li; if (jb > SEQ - 1) jb = SEQ - 1;                    \
      KFN[0] = *(const bfx8*)(kb + (size_t)ja * HDIM + lg * 8);                 \
      KFN[1] = *(const bfx8*)(kb + (size_t)ja * HDIM + 32 + lg * 8);            \
      KFN[2] = *(const bfx8*)(kb + (size_t)jb * HDIM + lg * 8);                 \
      KFN[3] = *(const bfx8*)(kb + (size_t)jb * HDIM + 32 + lg * 8);            \
    }                                                                           \
    f32x4 s0 = zero, s1 = zero;                                                 \
    s0 = __builtin_amdgcn_mfma_f32_16x16x32_bf16(qa[0], KFC[0], s0, 0, 0, 0);   \
    s0 = __builtin_amdgcn_mfma_f32_16x16x32_bf16(qa[1], KFC[1], s0, 0, 0, 0);   \
    s1 = __builtin_amdgcn_mfma_f32_16x16x32_bf16(qa[0], KFC[2], s1, 0, 0, 0);   \
    s1 = __builtin_amdgcn_mfma_f32_16x16x32_bf16(qa[1], KFC[3], s1, 0, 0, 0);   \
    const bool interior = (j0 >= i0 + 15 - half) && (j0 + 31 <= i0 + half) &&   \
                          (j0 + 31 <= SEQ - 1);                                 \
    if (interior) {                                                             \
      _Pragma("unroll") for (int r = 0; r < 4; ++r) {                           \
        const float p0 = exp2f(s0[r] * SCL);                                    \
        const float p1 = exp2f(s1[r] * SCL);                                    \
        lr[r] += p0 + p1;                                                       \
        P[PAR][lg * 4 + r][li] = f2bf(p0);                                      \
        P[PAR][lg * 4 + r][16 + li] = f2bf(p1);                                 \
      }                                                                         \
    } else {                                                                    \
      _Pragma("unroll") for (int r = 0; r < 4; ++r) {                           \
        const int i = i0 + lg * 4 + r;                                          \
        const int ja = j0 + li, jb = j0 + 16 + li;                              \
        int da = i - ja; if (da < 0) da = -da;                                  \
        int db = i - jb; if (db < 0) db = -db;                                  \
        const bool oka = (ja <= SEQ - 1) && (da <= half || ja == 0);            \
        const bool okb = (jb <= SEQ - 1) && (db <= half);                       \
        const float p0 = exp2f(fmaf(s0[r], SCL, oka ? 0.f : -1e5f));            \
        const float p1 = exp2f(fmaf(s1[r], SCL, okb ? 0.f : -1e5f));            \
        lr[r] += p0 + p1;                                                       \
        P[PAR][lg * 4 + r][li] = f2bf(p0);                                      \
        P[PAR][lg * 4 + r][16 + li] = f2bf(p1);                                 \
      }                                                                         \
    }                                                                           \
    const bfx8 pa = *(const bfx8*)(&P[PAR][li][lg * 8]);                        \
    ctxa[0] = __builtin_amdgcn_mfma_f32_16x16x32_bf16(pa, vf0, ctxa[0], 0, 0, 0);\
    ctxa[1] = __builtin_amdgcn_mfma_f32_16x16x32_bf16(pa, vf1, ctxa[1], 0, 0, 0);\
    ctxa[2] = __builtin_amdgcn_mfma_f32_16x16x32_bf16(pa, vf2, ctxa[2], 0, 0, 0);\
    ctxa[3] = __builtin_amdgcn_mfma_f32_16x16x32_bf16(pa, vf3, ctxa[3], 0, 0, 0);\
  }

__global__ __launch_bounds__(64) void attn_kernel(
    const u16* __restrict__ q, const u16* __restrict__ k,
    const u16* __restrict__ vt, u16* __restrict__ ctx,
    const int* __restrict__ wsz) {
  const int lane = threadIdx.x;
  const int li = lane & 15, lg = lane >> 4;
  // bijective XCD swizzle (4096 % 8 == 0): each XCD gets 4 contiguous (b,h)
  // pairs -> 2MB KV working set, L2-resident.
  const int bid = blockIdx.x;
  const int wid = (bid & 7) * 512 + (bid >> 3);
  const int qt = wid & 127;
  const int h = (wid >> 7) & 15;
  const int b = wid >> 11;
  const int i0 = qt * 16;
  const int bh = b * HEADS + h;
  const int half = wsz[0] >> 1;
  const float SCL = 0.125f * LOG2E;  // 1/sqrt(64) folded into exp2

  __shared__ alignas(16) u16 P[2][16][40];

  const u16* qb = q + (size_t)bh * SEQ * HDIM;
  const u16* kb = k + (size_t)bh * SEQ * HDIM;
  const u16* vb = vt + (size_t)bh * HDIM * SEQ;

  bfx8 qa[2];
#pragma unroll
  for (int ks = 0; ks < 2; ++ks)
    qa[ks] = *(const bfx8*)(qb + (size_t)(i0 + li) * HDIM + ks * 32 + lg * 8);

  int wlo = i0 - half; if (wlo < 0) wlo = 0; wlo &= ~31;
  int whi = i0 + 15 + half; if (whi > SEQ - 1) whi = SEQ - 1;
  const int nc = ((whi - wlo) >> 5) + 1;

  float lr[4] = {0.f, 0.f, 0.f, 0.f};
  f32x4 ctxa[4];
  const f32x4 zero = {0.f, 0.f, 0.f, 0.f};
#pragma unroll
  for (int dt = 0; dt < 4; ++dt) ctxa[dt] = zero;

  bfx8 kfA[4], kfB[4];
  {
    int ja = wlo + li;      if (ja > SEQ - 1) ja = SEQ - 1;
    int jb = wlo + 16 + li; if (jb > SEQ - 1) jb = SEQ - 1;
    kfA[0] = *(const bfx8*)(kb + (size_t)ja * HDIM + lg * 8);
    kfA[1] = *(const bfx8*)(kb + (size_t)ja * HDIM + 32 + lg * 8);
    kfA[2] = *(const bfx8*)(kb + (size_t)jb * HDIM + lg * 8);
    kfA[3] = *(const bfx8*)(kb + (size_t)jb * HDIM + 32 + lg * 8);
  }

  int c = 0;
  while (true) {
    ATTN_STEP(kfA, kfB, 0); if (++c >= nc) break;
    ATTN_STEP(kfB, kfA, 1); if (++c >= nc) break;
  }

  // final l reduction across the 16 key-columns (once, not per chunk)
#pragma unroll
  for (int r = 0; r < 4; ++r) {
    lr[r] += __shfl_xor(lr[r], 1);
    lr[r] += __shfl_xor(lr[r], 2);
    lr[r] += __shfl_xor(lr[r], 4);
    lr[r] += __shfl_xor(lr[r], 8);
  }

  // global j=0 column via VALU dot (only when not covered by the window chunks)
  if (wlo > 0) {
    const bfx8 k0a = *(const bfx8*)(kb + lg * 8);
    const bfx8 k0b = *(const bfx8*)(kb + 32 + lg * 8);
    float sg = 0.f;
#pragma unroll
    for (int e = 0; e < 8; ++e)
      sg += (float)qa[0][e] * (float)k0a[e] + (float)qa[1][e] * (float)k0b[e];
    sg += __shfl_xor(sg, 16);
    sg += __shfl_xor(sg, 32);
    const float pg = exp2f(sg * SCL);  // p(j=0) for query index li
    float v0[4];
#pragma unroll
    for (int dt = 0; dt < 4; ++dt) v0[dt] = bf2f(vb[(size_t)(dt * 16 + li) * SEQ]);
#pragma unroll
    for (int r = 0; r < 4; ++r) {
      const float pq = __shfl(pg, lg * 4 + r);
      lr[r] += pq;
#pragma unroll
      for (int dt = 0; dt < 4; ++dt) ctxa[dt][r] += pq * v0[dt];
    }
  }

#pragma unroll
  for (int r = 0; r < 4; ++r) {
    const float inv = 1.0f / lr[r];
    const int i = i0 + lg * 4 + r;
    const size_t base = ((size_t)b * SEQ + i) * HIDDEN + h * HDIM;
#pragma unroll
    for (int dt = 0; dt < 4; ++dt)
      ctx[base + dt * 16 + li] = f2bf(ctxa[dt][r] * inv);
  }
}

extern "C" void kernel_launch(void* const* d_in, const int* in_sizes, int n_in,
                              void* d_out, int out_size, void* d_ws, size_t ws_size,
                              hipStream_t stream) {
  const float* hs = (const float*)d_in[0];
  const float* Wq = (const float*)d_in[1];
  const float* bq = (const float*)d_in[2];
  const float* Wk = (const float*)d_in[3];
  const float* bk = (const float*)d_in[4];
  const float* Wv = (const float*)d_in[5];
  const float* bv = (const float*)d_in[6];
  const float* Wo = (const float*)d_in[7];
  const float* bo = (const float*)d_in[8];
  const int* wsz  = (const int*)d_in[9];
  float* out = (float*)d_out;

  const int BS = in_sizes[0] / HIDDEN;  // B*S = 4096
  (void)ws_size; (void)n_in; (void)out_size;

  u16* ws    = (u16*)d_ws;
  u16* hsb   = ws;                                  // [BS][1024] bf16 (reused as ctx)
  u16* wqkvt = hsb + (size_t)BS * HIDDEN;           // [3072][1024] bf16 (Wqkv^T)
  u16* wot   = wqkvt + (size_t)3 * HIDDEN * HIDDEN; // [1024][1024] bf16 (Wo^T)
  u16* qb    = wot + (size_t)HIDDEN * HIDDEN;       // [B*H][S][64]
  u16* kb    = qb + (size_t)BS * HIDDEN;
  u16* vtb   = kb + (size_t)BS * HIDDEN;            // [B*H][64][S]  (V^T)
  u16* ctxb  = hsb;                                 // alias: hsb dead after QKV GEMM

  cast_bf16_kernel<<<dim3(1024), dim3(256), 0, stream>>>(hs, hsb, BS * HIDDEN / 4);
  transpose_cast4_kernel<<<dim3(16, 16, 4), dim3(256), 0, stream>>>(Wq, Wk, Wv, Wo, wqkvt);

  gemm_qkv_kernel<<<dim3(3 * HIDDEN / 128, BS / 128), dim3(256), 0, stream>>>(
      hsb, wqkvt, bq, bk, bv, qb, kb, vtb);

  attn_kernel<<<dim3(4096), dim3(64), 0, stream>>>(qb, kb, vtb, ctxb, wsz);

  gemm_out_kernel<<<dim3(HIDDEN / 128, BS / 128), dim3(256), 0, stream>>>(ctxb, wot, bo, out);
}